// Round 5
// baseline (93.711 us; speedup 1.0000x reference)
//
#include <hip/hip_runtime.h>

#define NTOK 2048

typedef __attribute__((ext_vector_type(8))) short s8v;
typedef __attribute__((ext_vector_type(4))) float f32x4;

__device__ inline unsigned short f2bf(float f) {
  unsigned u = __builtin_bit_cast(unsigned, f);
  u += 0x7FFFu + ((u >> 16) & 1u);
  return (unsigned short)(u >> 16);
}
__device__ inline unsigned fkey(float f) {
  unsigned u = __builtin_bit_cast(unsigned, f);
  return (u & 0x80000000u) ? ~u : (u | 0x80000000u);
}
__device__ inline float kdec(unsigned k) {
  unsigned u = (k & 0x80000000u) ? (k ^ 0x80000000u) : ~k;
  return __builtin_bit_cast(float, u);
}

// ---- Kernel 0: init the atomic min/max cells (graph-capture safe) ----
__global__ void gat_init(unsigned* gmaxk, unsigned* gmink) {
  int t = threadIdx.x;
  if (t < 8) { gmaxk[t] = 0u; gmink[t] = 0xFFFFFFFFu; }
}

// ---- Kernel A: Wh = h@W, f1/f2 = Wh@a1/a2, WhT = bf16(Wh)^T, f2 min/max ----
__global__ __launch_bounds__(256) void gat_pre(
    const float* __restrict__ h, const float* __restrict__ W,
    const float* __restrict__ a, unsigned short* __restrict__ WhT,
    float* __restrict__ f1, float* __restrict__ f2,
    unsigned* __restrict__ gmaxk, unsigned* __restrict__ gmink) {
  __shared__ float wL[128 * 64];            // 32 KB
  __shared__ float hL[16 * 128];            // 8 KB
  __shared__ unsigned short tL[64 * 16];    // 2 KB transpose buffer
  __shared__ float bmx[4], bmn[4];
  int t = threadIdx.x;
  {
    const float4* W4 = (const float4*)W;
    float4* wL4 = (float4*)wL;
#pragma unroll
    for (int k = 0; k < 8; ++k) wL4[t + 256 * k] = W4[t + 256 * k];
    const float4* h4 = (const float4*)(h + (size_t)blockIdx.x * 16 * 128);
    float4* hL4 = (float4*)hL;
#pragma unroll
    for (int k = 0; k < 2; ++k) hL4[t + 256 * k] = h4[t + 256 * k];
  }
  __syncthreads();
  int w = t >> 6, lane = t & 63;
  float acc[4] = {0.f, 0.f, 0.f, 0.f};
  for (int kc = 0; kc < 128; kc += 32) {
    float wreg[32];
#pragma unroll
    for (int kk = 0; kk < 32; ++kk) wreg[kk] = wL[(kc + kk) * 64 + lane];
#pragma unroll
    for (int r = 0; r < 4; ++r) {
      const float* hrow = &hL[(w * 4 + r) * 128 + kc];
#pragma unroll
      for (int kk = 0; kk < 32; kk += 4) {
        float4 hv = *(const float4*)(hrow + kk);
        acc[r] += hv.x * wreg[kk] + hv.y * wreg[kk + 1] +
                  hv.z * wreg[kk + 2] + hv.w * wreg[kk + 3];
      }
    }
  }
  float a1 = a[lane], a2 = a[lane + 64];
  int row0 = blockIdx.x * 16 + w * 4;
  float wmx = -3.4e38f, wmn = 3.4e38f;
#pragma unroll
  for (int r = 0; r < 4; ++r) {
    int row = row0 + r;
    float v1 = acc[r] * a1, v2 = acc[r] * a2;
#pragma unroll
    for (int s = 32; s; s >>= 1) {
      v1 += __shfl_xor(v1, s, 64);
      v2 += __shfl_xor(v2, s, 64);
    }
    if (lane == 0) { f1[row] = v1; f2[row] = v2; }
    wmx = fmaxf(wmx, v2);
    wmn = fminf(wmn, v2);
    tL[lane * 16 + w * 4 + r] = f2bf(acc[r]);
  }
  if (lane == 0) { bmx[w] = wmx; bmn[w] = wmn; }
  __syncthreads();
  int b = (blockIdx.x * 16) / NTOK;
  if (t == 0) {
    float mx = fmaxf(fmaxf(bmx[0], bmx[1]), fmaxf(bmx[2], bmx[3]));
    float mn = fminf(fminf(bmn[0], bmn[1]), fminf(bmn[2], bmn[3]));
    atomicMax(&gmaxk[b], fkey(mx));
    atomicMin(&gmink[b], fkey(mn));
  }
  // coalesced bf16 write of WhT[b][feat][tok]
  int tok0 = (blockIdx.x * 16) % NTOK;
  int feat = t >> 2, rl = (t & 3) * 4;
  uint2 v = *(const uint2*)&tL[feat * 16 + rl];
  *(uint2*)(WhT + ((size_t)b * 64 + feat) * NTOK + tok0 + rl) = v;
}

// ---- Kernel B: fused mask+softmax+PV, software-pipelined. ----
// grid (128,8), 256 thr = 4 waves. Wave w: k-slice [w*512, w*512+512) for the
// block's 16 rows, as 16 chunks of K=32, double-buffered in registers so one
// chunk's loads are always in flight while the previous chunk computes.
struct Buf {
  int4 aa0, aa1;
  float4 v0, v1;
  s8v bf0, bf1, bf2, bf3;
};

__device__ inline Buf ldchunk(const int* __restrict__ arow,
                              const float* __restrict__ f2p,
                              const unsigned short* __restrict__ bp0, int k) {
  Buf u;
  u.aa0 = *(const int4*)(arow + k);
  u.aa1 = *(const int4*)(arow + k + 4);
  u.v0 = *(const float4*)(f2p + k);
  u.v1 = *(const float4*)(f2p + k + 4);
  const unsigned short* bp = bp0 + k;
  u.bf0 = *(const s8v*)(bp);
  u.bf1 = *(const s8v*)(bp + 16 * NTOK);
  u.bf2 = *(const s8v*)(bp + 32 * NTOK);
  u.bf3 = *(const s8v*)(bp + 48 * NTOK);
  return u;
}

__global__ __launch_bounds__(256, 4) void gat_main(
    const int* __restrict__ adj, const unsigned short* __restrict__ WhT,
    const float* __restrict__ f1, const float* __restrict__ f2,
    const unsigned* __restrict__ gmaxk, const unsigned* __restrict__ gmink,
    float* __restrict__ out) {
  __shared__ float red[4 * 16 * 68];  // [wave][row][feat(pad 68)] ~17.4 KB
  __shared__ float sums[4 * 16];
  int t = threadIdx.x;
  int b = blockIdx.y;
  int i0 = blockIdx.x * 16;
  int w = t >> 6, lane = t & 63, l15 = lane & 15, lhi = lane >> 4;

  float f1v = f1[(size_t)b * NTOK + i0 + l15];
  float gmx = kdec(gmaxk[b]), gmn = kdec(gmink[b]);
  float mr = fmaxf(f1v * gmx, f1v * gmn);
  float m = fmaxf(mr, 0.01f * mr);  // leaky_relu(mr) >= all leaky(f1v*f2[j])

  const int* arow = adj + ((size_t)b * NTOK + i0 + l15) * NTOK;
  const float* f2p = f2 + (size_t)b * NTOK;
  const unsigned short* bp0 = WhT + (size_t)b * 64 * NTOK + (size_t)l15 * NTOK;

  f32x4 ac0 = {0.f, 0.f, 0.f, 0.f}, ac1 = ac0, ac2 = ac0, ac3 = ac0;
  float ssum = 0.f;
  int kw = w * 512 + lhi * 8;

#define COMPUTE(U)                                                          \
  {                                                                         \
    float sv[8] = {f1v * U.v0.x, f1v * U.v0.y, f1v * U.v0.z, f1v * U.v0.w,  \
                   f1v * U.v1.x, f1v * U.v1.y, f1v * U.v1.z, f1v * U.v1.w}; \
    int am[8] = {U.aa0.x, U.aa0.y, U.aa0.z, U.aa0.w,                        \
                 U.aa1.x, U.aa1.y, U.aa1.z, U.aa1.w};                       \
    s8v af;                                                                 \
    _Pragma("unroll") for (int q = 0; q < 8; ++q) {                         \
      float s = sv[q];                                                      \
      float lk = fmaxf(s, 0.01f * s);                                       \
      float pe = __expf(lk - m);                                            \
      float p = am[q] > 0 ? pe : 0.f;                                       \
      ssum += p;                                                            \
      unsigned uu = __builtin_bit_cast(unsigned, p) + 0x8000u;              \
      af[q] = (short)(uu >> 16);                                            \
    }                                                                       \
    ac0 = __builtin_amdgcn_mfma_f32_16x16x32_bf16(af, U.bf0, ac0, 0, 0, 0); \
    ac1 = __builtin_amdgcn_mfma_f32_16x16x32_bf16(af, U.bf1, ac1, 0, 0, 0); \
    ac2 = __builtin_amdgcn_mfma_f32_16x16x32_bf16(af, U.bf2, ac2, 0, 0, 0); \
    ac3 = __builtin_amdgcn_mfma_f32_16x16x32_bf16(af, U.bf3, ac3, 0, 0, 0); \
  }

  Buf cur = ldchunk(arow, f2p, bp0, kw);
#pragma unroll
  for (int ch = 0; ch < 16; ++ch) {
    Buf nxt;
    if (ch < 15) nxt = ldchunk(arow, f2p, bp0, kw + (ch + 1) * 32);
    COMPUTE(cur);
    cur = nxt;
  }
#undef COMPUTE

  // row-sum: reduce over the 4 lanes sharing l15 (lhi = 0..3)
  ssum += __shfl_xor(ssum, 16, 64);
  ssum += __shfl_xor(ssum, 32, 64);
  if (lane < 16) sums[w * 16 + l15] = ssum;

  // C partials: row = lhi*4+reg, col(feat) = ft*16+l15
#pragma unroll
  for (int reg = 0; reg < 4; ++reg) {
    int row = lhi * 4 + reg;
    float* dst = &red[w * 1088 + row * 68 + l15];
    dst[0] = ac0[reg];
    dst[16] = ac1[reg];
    dst[32] = ac2[reg];
    dst[48] = ac3[reg];
  }
  __syncthreads();

  // epilogue: 1024 outputs / 256 threads
#pragma unroll
  for (int rep = 0; rep < 4; ++rep) {
    int idx = t + rep * 256;
    int mm = idx >> 6, f = idx & 63;
    float v = 0.f, dn = 0.f;
#pragma unroll
    for (int w2 = 0; w2 < 4; ++w2) {
      v += red[w2 * 1088 + mm * 68 + f];
      dn += sums[w2 * 16 + mm];
    }
    float rdn = dn > 0.f ? 1.0f / dn : 0.f;
    float hp = v * rdn;
    float o = hp > 0.f ? hp : expm1f(hp);
    out[((size_t)b * NTOK + i0 + mm) * 64 + f] = o;
  }
}

extern "C" void kernel_launch(void* const* d_in, const int* in_sizes, int n_in,
                              void* d_out, int out_size, void* d_ws, size_t ws_size,
                              hipStream_t stream) {
  const float* h = (const float*)d_in[0];
  const int* adj = (const int*)d_in[1];
  const float* W = (const float*)d_in[2];
  const float* a = (const float*)d_in[3];
  float* out = (float*)d_out;

  unsigned short* WhT = (unsigned short*)d_ws;              // 2 MB
  float* f1 = (float*)((char*)d_ws + 2 * 1024 * 1024);      // 64 KB
  float* f2 = f1 + 16384;                                   // 64 KB
  unsigned* gmaxk = (unsigned*)(f2 + 16384);                // 32 B
  unsigned* gmink = gmaxk + 8;                              // 32 B

  gat_init<<<1, 64, 0, stream>>>(gmaxk, gmink);
  gat_pre<<<1024, 256, 0, stream>>>(h, W, a, WhT, f1, f2, gmaxk, gmink);
  gat_main<<<dim3(128, 8), 256, 0, stream>>>(adj, WhT, f1, f2, gmaxk, gmink, out);
}

// Round 6
// 86.853 us; speedup vs baseline: 1.0790x; 1.0790x over previous
//
#include <hip/hip_runtime.h>

#define NTOK 2048

typedef __attribute__((ext_vector_type(8))) short s8v;
typedef __attribute__((ext_vector_type(4))) float f32x4;

__device__ inline unsigned short f2bf(float f) {
  unsigned u = __builtin_bit_cast(unsigned, f);
  u += 0x7FFFu + ((u >> 16) & 1u);
  return (unsigned short)(u >> 16);
}
__device__ inline unsigned fkey(float f) {
  unsigned u = __builtin_bit_cast(unsigned, f);
  return (u & 0x80000000u) ? ~u : (u | 0x80000000u);
}
__device__ inline float kdec(unsigned k) {
  unsigned u = (k & 0x80000000u) ? (k ^ 0x80000000u) : ~k;
  return __builtin_bit_cast(float, u);
}

// ---- Kernel 0: init the atomic min/max cells (graph-capture safe) ----
__global__ void gat_init(unsigned* gmaxk, unsigned* gmink) {
  int t = threadIdx.x;
  if (t < 8) { gmaxk[t] = 0u; gmink[t] = 0xFFFFFFFFu; }
}

// ---- Kernel P: dense bitpack adj (128 MB) -> swizzled bitmask (4 MB) ----
// Byte g covers adj[g*8 .. g*8+8). Output byte index permutes the low 6 bits
// so that gat_main lane (l15,lhi) of wave w reads its 16 chunk-bytes as one
// uint4 at row*256 + w*64 + lhi*16:  o6 = (g%4)*16 + (g/4)%16.
__global__ __launch_bounds__(256) void gat_pack(
    const int* __restrict__ adj, unsigned char* __restrict__ mask) {
  int g = blockIdx.x * 256 + threadIdx.x;
  const int4* a4 = (const int4*)(adj + (size_t)g * 8);
  int4 x = a4[0];
  int4 y = a4[1];
  unsigned byte = (unsigned)(x.x > 0) | ((unsigned)(x.y > 0) << 1) |
                  ((unsigned)(x.z > 0) << 2) | ((unsigned)(x.w > 0) << 3) |
                  ((unsigned)(y.x > 0) << 4) | ((unsigned)(y.y > 0) << 5) |
                  ((unsigned)(y.z > 0) << 6) | ((unsigned)(y.w > 0) << 7);
  int o = (g & ~63) | ((g & 3) << 4) | ((g >> 2) & 15);
  mask[o] = (unsigned char)byte;
}

// ---- Kernel A: Wh = h@W, f1/f2 = Wh@a1/a2, WhT = bf16(Wh)^T, f2 min/max ----
// 64 rows per block (W staged once per 64 rows). 256 thr = 4 waves.
__global__ __launch_bounds__(256) void gat_pre(
    const float* __restrict__ h, const float* __restrict__ W,
    const float* __restrict__ a, unsigned short* __restrict__ WhT,
    float* __restrict__ f1, float* __restrict__ f2,
    unsigned* __restrict__ gmaxk, unsigned* __restrict__ gmink) {
  __shared__ float wL[128 * 64];            // 32 KB
  __shared__ float hL[64 * 128];            // 32 KB
  __shared__ unsigned short tL[64 * 66];    // 8.25 KB [feat][tok] pad 66
  __shared__ float bmx[4], bmn[4];
  int t = threadIdx.x;
  {
    const float4* W4 = (const float4*)W;
    float4* wL4 = (float4*)wL;
#pragma unroll
    for (int k = 0; k < 8; ++k) wL4[t + 256 * k] = W4[t + 256 * k];
    const float4* h4 = (const float4*)(h + (size_t)blockIdx.x * 64 * 128);
    float4* hL4 = (float4*)hL;
#pragma unroll
    for (int k = 0; k < 8; ++k) hL4[t + 256 * k] = h4[t + 256 * k];
  }
  __syncthreads();
  int w = t >> 6, lane = t & 63;
  float acc[16];
#pragma unroll
  for (int r = 0; r < 16; ++r) acc[r] = 0.f;
  for (int kc = 0; kc < 128; kc += 32) {
    float wreg[32];
#pragma unroll
    for (int kk = 0; kk < 32; ++kk) wreg[kk] = wL[(kc + kk) * 64 + lane];
#pragma unroll
    for (int r = 0; r < 16; ++r) {
      const float* hrow = &hL[(w * 16 + r) * 128 + kc];
#pragma unroll
      for (int kk = 0; kk < 32; kk += 4) {
        float4 hv = *(const float4*)(hrow + kk);
        acc[r] += hv.x * wreg[kk] + hv.y * wreg[kk + 1] +
                  hv.z * wreg[kk + 2] + hv.w * wreg[kk + 3];
      }
    }
  }
  float a1 = a[lane], a2 = a[lane + 64];
  int row0 = blockIdx.x * 64 + w * 16;
  float wmx = -3.4e38f, wmn = 3.4e38f;
#pragma unroll
  for (int r = 0; r < 16; ++r) {
    float v1 = acc[r] * a1, v2 = acc[r] * a2;
#pragma unroll
    for (int s = 32; s; s >>= 1) {
      v1 += __shfl_xor(v1, s, 64);
      v2 += __shfl_xor(v2, s, 64);
    }
    if (lane == 0) { f1[row0 + r] = v1; f2[row0 + r] = v2; }
    wmx = fmaxf(wmx, v2);
    wmn = fminf(wmn, v2);
    tL[lane * 66 + w * 16 + r] = f2bf(acc[r]);
  }
  if (lane == 0) { bmx[w] = wmx; bmn[w] = wmn; }
  __syncthreads();
  int b = blockIdx.x >> 5;  // 32 blocks per batch
  if (t == 0) {
    float mx = fmaxf(fmaxf(bmx[0], bmx[1]), fmaxf(bmx[2], bmx[3]));
    float mn = fminf(fminf(bmn[0], bmn[1]), fminf(bmn[2], bmn[3]));
    atomicMax(&gmaxk[b], fkey(mx));
    atomicMin(&gmink[b], fkey(mn));
  }
  // WhT[b][feat][tok] write: 4 threads per feature, 64B-contiguous segments
  int tok0 = (blockIdx.x & 31) * 64;
  int f = t >> 2, sub = t & 3;
  const unsigned short* src = &tL[f * 66];
  unsigned short* dst = WhT + ((size_t)b * 64 + f) * NTOK + tok0;
  *(uint4*)(dst + sub * 8) = *(const uint4*)(src + sub * 8);
  *(uint4*)(dst + 32 + sub * 8) = *(const uint4*)(src + 32 + sub * 8);
}

// ---- Kernel B: fused mask+softmax+PV; adj replaced by L2-resident bitmask ----
// grid (128,8), 256 thr = 4 waves. Wave w: k-slice [w*512,+512) for 16 rows,
// 16 chunks of K=32. Lane (l15,lhi): A-frag row=l15, k=ch*32+lhi*8+q.
__global__ __launch_bounds__(256, 4) void gat_main(
    const unsigned char* __restrict__ mask, const unsigned short* __restrict__ WhT,
    const float* __restrict__ f1, const float* __restrict__ f2,
    const unsigned* __restrict__ gmaxk, const unsigned* __restrict__ gmink,
    float* __restrict__ out) {
  __shared__ float red[4 * 16 * 68];  // [wave][row][feat pad 68] ~17.4 KB
  __shared__ float sums[4 * 16];
  int t = threadIdx.x;
  int b = blockIdx.y;
  int i0 = blockIdx.x * 16;
  int w = t >> 6, lane = t & 63, l15 = lane & 15, lhi = lane >> 4;
  size_t gr = (size_t)b * NTOK + i0 + l15;

  float f1v = f1[gr];
  float gmx = kdec(gmaxk[b]), gmn = kdec(gmink[b]);
  float mr = fmaxf(f1v * gmx, f1v * gmn);
  float m = fmaxf(mr, 0.01f * mr);  // leaky_relu(mr) >= all leaky(f1v*f2[j])

  // whole 512-k mask slice for this lane: one uint4 (16 chunk-bytes)
  uint4 m4 = *(const uint4*)(mask + gr * 256 + w * 64 + lhi * 16);
  unsigned mw[4] = {m4.x, m4.y, m4.z, m4.w};

  const float* f2p = f2 + (size_t)b * NTOK;
  const unsigned short* bp0 = WhT + (size_t)b * 64 * NTOK + (size_t)l15 * NTOK;

  f32x4 ac0 = {0.f, 0.f, 0.f, 0.f}, ac1 = ac0, ac2 = ac0, ac3 = ac0;
  float ssum = 0.f;
  int kbase = w * 512 + lhi * 8;

#pragma unroll
  for (int ch = 0; ch < 16; ++ch) {
    int k = kbase + ch * 32;
    float4 v0 = *(const float4*)(f2p + k);
    float4 v1 = *(const float4*)(f2p + k + 4);
    const unsigned short* bp = bp0 + k;
    s8v bf0 = *(const s8v*)(bp);
    s8v bf1 = *(const s8v*)(bp + 16 * NTOK);
    s8v bf2 = *(const s8v*)(bp + 32 * NTOK);
    s8v bf3 = *(const s8v*)(bp + 48 * NTOK);
    unsigned byte = (mw[ch >> 2] >> ((ch & 3) * 8)) & 0xFFu;

    float sv[8] = {f1v * v0.x, f1v * v0.y, f1v * v0.z, f1v * v0.w,
                   f1v * v1.x, f1v * v1.y, f1v * v1.z, f1v * v1.w};
    s8v af;
#pragma unroll
    for (int q = 0; q < 8; ++q) {
      float s = sv[q];
      float lk = fmaxf(s, 0.01f * s);
      float pe = __expf(lk - m);
      float p = (byte & (1u << q)) ? pe : 0.f;
      ssum += p;
      unsigned uu = __builtin_bit_cast(unsigned, p) + 0x8000u;
      af[q] = (short)(uu >> 16);
    }
    ac0 = __builtin_amdgcn_mfma_f32_16x16x32_bf16(af, bf0, ac0, 0, 0, 0);
    ac1 = __builtin_amdgcn_mfma_f32_16x16x32_bf16(af, bf1, ac1, 0, 0, 0);
    ac2 = __builtin_amdgcn_mfma_f32_16x16x32_bf16(af, bf2, ac2, 0, 0, 0);
    ac3 = __builtin_amdgcn_mfma_f32_16x16x32_bf16(af, bf3, ac3, 0, 0, 0);
  }

  // row-sum: reduce over the 4 lanes sharing l15 (lhi = 0..3)
  ssum += __shfl_xor(ssum, 16, 64);
  ssum += __shfl_xor(ssum, 32, 64);
  if (lane < 16) sums[w * 16 + l15] = ssum;

  // C partials: row = lhi*4+reg, col(feat) = ft*16+l15
#pragma unroll
  for (int reg = 0; reg < 4; ++reg) {
    int row = lhi * 4 + reg;
    float* dst = &red[w * 1088 + row * 68 + l15];
    dst[0] = ac0[reg];
    dst[16] = ac1[reg];
    dst[32] = ac2[reg];
    dst[48] = ac3[reg];
  }
  __syncthreads();

  // epilogue: 1024 outputs / 256 threads
#pragma unroll
  for (int rep = 0; rep < 4; ++rep) {
    int idx = t + rep * 256;
    int mm = idx >> 6, f = idx & 63;
    float v = 0.f, dn = 0.f;
#pragma unroll
    for (int w2 = 0; w2 < 4; ++w2) {
      v += red[w2 * 1088 + mm * 68 + f];
      dn += sums[w2 * 16 + mm];
    }
    float rdn = dn > 0.f ? 1.0f / dn : 0.f;
    float hp = v * rdn;
    float o = hp > 0.f ? hp : expm1f(hp);
    out[((size_t)b * NTOK + i0 + mm) * 64 + f] = o;
  }
}

extern "C" void kernel_launch(void* const* d_in, const int* in_sizes, int n_in,
                              void* d_out, int out_size, void* d_ws, size_t ws_size,
                              hipStream_t stream) {
  const float* h = (const float*)d_in[0];
  const int* adj = (const int*)d_in[1];
  const float* W = (const float*)d_in[2];
  const float* a = (const float*)d_in[3];
  float* out = (float*)d_out;

  unsigned char* mask = (unsigned char*)d_ws;                   // 4 MB
  unsigned short* WhT = (unsigned short*)(mask + 4 * 1024 * 1024);  // 2 MB
  float* f1 = (float*)((char*)WhT + 2 * 1024 * 1024);           // 64 KB
  float* f2 = f1 + 16384;                                       // 64 KB
  unsigned* gmaxk = (unsigned*)(f2 + 16384);                    // 32 B
  unsigned* gmink = gmaxk + 8;                                  // 32 B

  gat_init<<<1, 64, 0, stream>>>(gmaxk, gmink);
  gat_pack<<<16384, 256, 0, stream>>>(adj, mask);
  gat_pre<<<256, 256, 0, stream>>>(h, W, a, WhT, f1, f2, gmaxk, gmink);
  gat_main<<<dim3(128, 8), 256, 0, stream>>>(mask, WhT, f1, f2, gmaxk, gmink, out);
}

// Round 7
// 80.613 us; speedup vs baseline: 1.1625x; 1.0774x over previous
//
#include <hip/hip_runtime.h>

#define NTOK 2048

typedef __attribute__((ext_vector_type(8))) short s8v;
typedef __attribute__((ext_vector_type(4))) float f32x4;

__device__ inline unsigned short f2bf(float f) {
  unsigned u = __builtin_bit_cast(unsigned, f);
  u += 0x7FFFu + ((u >> 16) & 1u);
  return (unsigned short)(u >> 16);
}
__device__ inline unsigned fkey(float f) {
  unsigned u = __builtin_bit_cast(unsigned, f);
  return (u & 0x80000000u) ? ~u : (u | 0x80000000u);
}
__device__ inline float kdec(unsigned k) {
  unsigned u = (k & 0x80000000u) ? (k ^ 0x80000000u) : ~k;
  return __builtin_bit_cast(float, u);
}

// ---- Kernel 0: init the atomic min/max cells (graph-capture safe) ----
__global__ void gat_init(unsigned* gmaxk, unsigned* gmink) {
  int t = threadIdx.x;
  if (t < 8) { gmaxk[t] = 0u; gmink[t] = 0xFFFFFFFFu; }
}

// ---- Kernel A: Wh = h@W, f1/f2 = Wh@a1/a2, WhT = bf16(Wh)^T, f2 min/max ----
// 64 rows per block (W staged once per 64 rows). 256 thr = 4 waves.
__global__ __launch_bounds__(256) void gat_pre(
    const float* __restrict__ h, const float* __restrict__ W,
    const float* __restrict__ a, unsigned short* __restrict__ WhT,
    float* __restrict__ f1, float* __restrict__ f2,
    unsigned* __restrict__ gmaxk, unsigned* __restrict__ gmink) {
  __shared__ float wL[128 * 64];            // 32 KB
  __shared__ float hL[64 * 128];            // 32 KB
  __shared__ unsigned short tL[64 * 66];    // 8.25 KB [feat][tok] pad 66
  __shared__ float bmx[4], bmn[4];
  int t = threadIdx.x;
  {
    const float4* W4 = (const float4*)W;
    float4* wL4 = (float4*)wL;
#pragma unroll
    for (int k = 0; k < 8; ++k) wL4[t + 256 * k] = W4[t + 256 * k];
    const float4* h4 = (const float4*)(h + (size_t)blockIdx.x * 64 * 128);
    float4* hL4 = (float4*)hL;
#pragma unroll
    for (int k = 0; k < 8; ++k) hL4[t + 256 * k] = h4[t + 256 * k];
  }
  __syncthreads();
  int w = t >> 6, lane = t & 63;
  float acc[16];
#pragma unroll
  for (int r = 0; r < 16; ++r) acc[r] = 0.f;
  for (int kc = 0; kc < 128; kc += 32) {
    float wreg[32];
#pragma unroll
    for (int kk = 0; kk < 32; ++kk) wreg[kk] = wL[(kc + kk) * 64 + lane];
#pragma unroll
    for (int r = 0; r < 16; ++r) {
      const float* hrow = &hL[(w * 16 + r) * 128 + kc];
#pragma unroll
      for (int kk = 0; kk < 32; kk += 4) {
        float4 hv = *(const float4*)(hrow + kk);
        acc[r] += hv.x * wreg[kk] + hv.y * wreg[kk + 1] +
                  hv.z * wreg[kk + 2] + hv.w * wreg[kk + 3];
      }
    }
  }
  float a1 = a[lane], a2 = a[lane + 64];
  int row0 = blockIdx.x * 64 + w * 16;
  float wmx = -3.4e38f, wmn = 3.4e38f;
#pragma unroll
  for (int r = 0; r < 16; ++r) {
    float v1 = acc[r] * a1, v2 = acc[r] * a2;
#pragma unroll
    for (int s = 32; s; s >>= 1) {
      v1 += __shfl_xor(v1, s, 64);
      v2 += __shfl_xor(v2, s, 64);
    }
    if (lane == 0) { f1[row0 + r] = v1; f2[row0 + r] = v2; }
    wmx = fmaxf(wmx, v2);
    wmn = fminf(wmn, v2);
    tL[lane * 66 + w * 16 + r] = f2bf(acc[r]);
  }
  if (lane == 0) { bmx[w] = wmx; bmn[w] = wmn; }
  __syncthreads();
  int b = blockIdx.x >> 5;  // 32 blocks per batch
  if (t == 0) {
    float mx = fmaxf(fmaxf(bmx[0], bmx[1]), fmaxf(bmx[2], bmx[3]));
    float mn = fminf(fminf(bmn[0], bmn[1]), fminf(bmn[2], bmn[3]));
    atomicMax(&gmaxk[b], fkey(mx));
    atomicMin(&gmink[b], fkey(mn));
  }
  // WhT[b][feat][tok] write: 4 threads per feature, 64B-contiguous segments
  int tok0 = (blockIdx.x & 31) * 64;
  int f = t >> 2, sub = t & 3;
  const unsigned short* src = &tL[f * 66];
  unsigned short* dst = WhT + ((size_t)b * 64 + f) * NTOK + tok0;
  *(uint4*)(dst + sub * 8) = *(const uint4*)(src + sub * 8);
  *(uint4*)(dst + 32 + sub * 8) = *(const uint4*)(src + 32 + sub * 8);
}

// ---- Kernel B: stream adj -> LDS bitmask, then fused mask+softmax+PV ----
// grid (128,8), 256 thr = 4 waves. Stage: 16 rows x 8 KB adj read as
// lane-contiguous int4 stream, bitpacked (shfl nibble merge) into a 4 KB
// swizzled LDS mask tile. Compute: wave w handles k-slice [w*512,+512) for
// all 16 rows; lane (l15,lhi): A-frag row=l15, k=ch*32+lhi*8+q; scores in
// fragment layout; safe row-max bound from per-batch f2 min/max.
__global__ __launch_bounds__(256, 4) void gat_main(
    const int* __restrict__ adj, const unsigned short* __restrict__ WhT,
    const float* __restrict__ f1, const float* __restrict__ f2,
    const unsigned* __restrict__ gmaxk, const unsigned* __restrict__ gmink,
    float* __restrict__ out) {
  __shared__ __align__(16) unsigned char mLDS[16 * 256];  // 4 KB swizzled mask
  __shared__ float red[4 * 16 * 68];  // [wave][row][feat pad 68] ~17.4 KB
  __shared__ float sums[4 * 16];
  int t = threadIdx.x;
  int b = blockIdx.y;
  int i0 = blockIdx.x * 16;
  int w = t >> 6, lane = t & 63, l15 = lane & 15, lhi = lane >> 4;

  // ---- stage: bitpack this block's 16 adj rows into LDS ----
  // int4 idx = p*256 + t over the 16x2048 tile (512 int4 per row), p=0..31.
  const int4* adj4 = (const int4*)(adj + ((size_t)b * NTOK + i0) * NTOK);
#pragma unroll
  for (int grp = 0; grp < 4; ++grp) {
    int4 v[8];
#pragma unroll
    for (int i = 0; i < 8; ++i) v[i] = adj4[(grp * 8 + i) * 256 + t];
#pragma unroll
    for (int i = 0; i < 8; ++i) {
      int idx = (grp * 8 + i) * 256 + t;
      unsigned nib = (unsigned)(v[i].x > 0) | ((unsigned)(v[i].y > 0) << 1) |
                     ((unsigned)(v[i].z > 0) << 2) | ((unsigned)(v[i].w > 0) << 3);
      unsigned pn = (unsigned)__shfl_xor((int)nib, 1, 64);
      if (!(t & 1)) {
        unsigned byte = nib | (pn << 4);
        int row = idx >> 9;
        int B = (idx & 511) >> 1;
        int pos = row * 256 + (B & ~63) + ((B & 3) << 4) + ((B >> 2) & 15);
        mLDS[pos] = (unsigned char)byte;
      }
    }
  }

  float f1v = f1[(size_t)b * NTOK + i0 + l15];
  float gmx = kdec(gmaxk[b]), gmn = kdec(gmink[b]);
  float mr = fmaxf(f1v * gmx, f1v * gmn);
  float m = fmaxf(mr, 0.01f * mr);  // leaky_relu(mr) >= all leaky(f1v*f2[j])

  __syncthreads();

  // whole 512-k mask slice for this lane: one uint4 (16 chunk-bytes)
  uint4 m4 = *(const uint4*)(mLDS + l15 * 256 + w * 64 + lhi * 16);
  unsigned mw[4] = {m4.x, m4.y, m4.z, m4.w};

  const float* f2p = f2 + (size_t)b * NTOK;
  const unsigned short* bp0 = WhT + (size_t)b * 64 * NTOK + (size_t)l15 * NTOK;

  f32x4 ac0 = {0.f, 0.f, 0.f, 0.f}, ac1 = ac0, ac2 = ac0, ac3 = ac0;
  float ssum = 0.f;
  int kbase = w * 512 + lhi * 8;

#pragma unroll
  for (int ch = 0; ch < 16; ++ch) {
    int k = kbase + ch * 32;
    float4 v0 = *(const float4*)(f2p + k);
    float4 v1 = *(const float4*)(f2p + k + 4);
    const unsigned short* bp = bp0 + k;
    s8v bf0 = *(const s8v*)(bp);
    s8v bf1 = *(const s8v*)(bp + 16 * NTOK);
    s8v bf2 = *(const s8v*)(bp + 32 * NTOK);
    s8v bf3 = *(const s8v*)(bp + 48 * NTOK);
    unsigned byte = (mw[ch >> 2] >> ((ch & 3) * 8)) & 0xFFu;

    float sv[8] = {f1v * v0.x, f1v * v0.y, f1v * v0.z, f1v * v0.w,
                   f1v * v1.x, f1v * v1.y, f1v * v1.z, f1v * v1.w};
    s8v af;
#pragma unroll
    for (int q = 0; q < 8; ++q) {
      float s = sv[q];
      float lk = fmaxf(s, 0.01f * s);
      float pe = __expf(lk - m);
      float p = (byte & (1u << q)) ? pe : 0.f;
      ssum += p;
      unsigned uu = __builtin_bit_cast(unsigned, p) + 0x8000u;
      af[q] = (short)(uu >> 16);
    }
    ac0 = __builtin_amdgcn_mfma_f32_16x16x32_bf16(af, bf0, ac0, 0, 0, 0);
    ac1 = __builtin_amdgcn_mfma_f32_16x16x32_bf16(af, bf1, ac1, 0, 0, 0);
    ac2 = __builtin_amdgcn_mfma_f32_16x16x32_bf16(af, bf2, ac2, 0, 0, 0);
    ac3 = __builtin_amdgcn_mfma_f32_16x16x32_bf16(af, bf3, ac3, 0, 0, 0);
  }

  // row-sum: reduce over the 4 lanes sharing l15 (lhi = 0..3)
  ssum += __shfl_xor(ssum, 16, 64);
  ssum += __shfl_xor(ssum, 32, 64);
  if (lane < 16) sums[w * 16 + l15] = ssum;

  // C partials: row = lhi*4+reg, col(feat) = ft*16+l15
#pragma unroll
  for (int reg = 0; reg < 4; ++reg) {
    int row = lhi * 4 + reg;
    float* dst = &red[w * 1088 + row * 68 + l15];
    dst[0] = ac0[reg];
    dst[16] = ac1[reg];
    dst[32] = ac2[reg];
    dst[48] = ac3[reg];
  }
  __syncthreads();

  // epilogue: 1024 outputs / 256 threads
#pragma unroll
  for (int rep = 0; rep < 4; ++rep) {
    int idx = t + rep * 256;
    int mm = idx >> 6, f = idx & 63;
    float v = 0.f, dn = 0.f;
#pragma unroll
    for (int w2 = 0; w2 < 4; ++w2) {
      v += red[w2 * 1088 + mm * 68 + f];
      dn += sums[w2 * 16 + mm];
    }
    float rdn = dn > 0.f ? 1.0f / dn : 0.f;
    float hp = v * rdn;
    float o = hp > 0.f ? hp : expm1f(hp);
    out[((size_t)b * NTOK + i0 + mm) * 64 + f] = o;
  }
}

extern "C" void kernel_launch(void* const* d_in, const int* in_sizes, int n_in,
                              void* d_out, int out_size, void* d_ws, size_t ws_size,
                              hipStream_t stream) {
  const float* h = (const float*)d_in[0];
  const int* adj = (const int*)d_in[1];
  const float* W = (const float*)d_in[2];
  const float* a = (const float*)d_in[3];
  float* out = (float*)d_out;

  unsigned short* WhT = (unsigned short*)d_ws;              // 2 MB
  float* f1 = (float*)((char*)d_ws + 2 * 1024 * 1024);      // 64 KB
  float* f2 = f1 + 16384;                                   // 64 KB
  unsigned* gmaxk = (unsigned*)(f2 + 16384);                // 32 B
  unsigned* gmink = gmaxk + 8;                              // 32 B

  gat_init<<<1, 64, 0, stream>>>(gmaxk, gmink);
  gat_pre<<<256, 256, 0, stream>>>(h, W, a, WhT, f1, f2, gmaxk, gmink);
  gat_main<<<dim3(128, 8), 256, 0, stream>>>(adj, WhT, f1, f2, gmaxk, gmink, out);
}